// Round 9
// baseline (1093.405 us; speedup 1.0000x reference)
//
#include <hip/hip_runtime.h>
#include <math.h>

// ---------------------------------------------------------------------------
// Round 9: 3 waves/SIMD, spill-free.
//   Evidence: 2 waves no-spill = 921 us (R6); 4 waves + 130 MB spill = 910 us
//   (R7/R8) -> occupancy gain was eaten by spill VALU. This round takes the
//   midpoint: 768-thr blocks (12 waves, launch_bounds(768,1) -> 3 waves/EU,
//   ~170-VGPR budget; R6 proved the structure fits 128 spill-free).
//   LDS 148.5 KB -> 1 block/CU. FFN1 transient split into two 4-tile halves
//   (peak live -16 regs) as insurance. Grid = 683 one-chunk blocks (192 rows).
// ---------------------------------------------------------------------------

constexpr int STEPS = 16;
constexpr int INDIM = 200;

typedef __attribute__((ext_vector_type(8))) short bfrag8;   // 8 bf16 = 4 VGPR
typedef __attribute__((ext_vector_type(4))) float f32x4;
typedef __attribute__((ext_vector_type(4))) short s16x4;

constexpr int FB_WIN  = 0;    // W_in: mt(4) x kt(7)
constexpr int NFRAG   = 140;
constexpr int NPARAM  = 1544;

// LDS-resident steady frag indices (= global index - 28)
constexpr int LB_ZQ   = 0;
constexpr int LB_ZK   = 8;
constexpr int LB_ZV   = 16;
constexpr int LB_ZOUT = 24;
constexpr int LB_ZF1  = 32;   // 8 m-tiles x 2 k-tiles
constexpr int LB_ZF2  = 48;
constexpr int LB_YV   = 64;
constexpr int LB_YOUT = 72;
constexpr int LB_YF1  = 80;
constexpr int LB_YF2  = 96;
constexpr int NSTEADY = 112;

// packed param float offsets
constexpr int PB_BIN   = 0;
constexpr int PB_GIN   = 64;
constexpr int PB_BEIN  = 128;
constexpr int PB_ZINB  = 192;
constexpr int PB_ZOUTB = 384;
constexpr int PB_ZF1B  = 448;
constexpr int PB_ZF2B  = 576;
constexpr int PB_ZN1G  = 640;
constexpr int PB_ZN1B  = 704;
constexpr int PB_ZN2G  = 768;
constexpr int PB_ZN2B  = 832;
constexpr int PB_YVB   = 896;
constexpr int PB_YOUTB = 960;
constexpr int PB_YF1B  = 1024;
constexpr int PB_YF2B  = 1152;
constexpr int PB_YN1G  = 1216;
constexpr int PB_YN1B  = 1280;
constexpr int PB_YN2G  = 1344;
constexpr int PB_YN2B  = 1408;
constexpr int PB_WOUT  = 1472;
constexpr int PB_BOUT  = 1536;

// LDS arena layout (shorts)
constexpr int S64      = 72;
constexpr int L_W      = 0;                       // 112 frags = 57,344 shorts
constexpr int L_P      = 57344;                   // 3,088 shorts
constexpr int L_ACT    = 60432;                   // 12 waves x TH(64-wide)
constexpr int WAVE_SH  = 1152;                    // 16 samples x 72 shorts
constexpr int NWAVE    = 12;
constexpr int ARENA_SH = L_ACT + NWAVE * WAVE_SH; // 74,256 shorts = 148,512 B

constexpr int BLK      = 64 * NWAVE;              // 768 threads
constexpr int ROWS_PB  = 16 * NWAVE;              // 192 rows per block

struct Params {
  const float *x, *W_in, *b_in, *g_in, *be_in;
  const float *z_in_w, *z_in_b, *z_out_w, *z_out_b;
  const float *z_ffn_w1, *z_ffn_b1, *z_ffn_w2, *z_ffn_b2;
  const float *zn1_g, *zn1_b, *zn2_g, *zn2_b;
  const float *y_in_w, *y_in_b, *y_out_w, *y_out_b;
  const float *y_ffn_w1, *y_ffn_b1, *y_ffn_w2, *y_ffn_b2;
  const float *yn1_g, *yn1_b, *yn2_g, *yn2_b;
  const float *W_out, *b_out;
  float *out;
  int nrows;
};

__device__ __forceinline__ ushort f2bf(float f) {
  uint u = __float_as_uint(f);
  u += 0x7FFFu + ((u >> 16) & 1u);
  return (ushort)(u >> 16);
}
__device__ __forceinline__ uint pk2(float a, float b) {
  return (uint)f2bf(a) | ((uint)f2bf(b) << 16);
}
__device__ __forceinline__ float upk_lo(uint u) {
  return __uint_as_float(u << 16);
}
__device__ __forceinline__ float upk_hi(uint u) {
  return __uint_as_float(u & 0xFFFF0000u);
}
__device__ __forceinline__ float dot4(f32x4 a, f32x4 b) {
  return a.x * b.x + a.y * b.y + a.z * b.z + a.w * b.w;
}
__device__ __forceinline__ void stc(short* buf, int stride, int mt, int q,
                                    int s, f32x4 c) {
  s16x4 v;
  v.x = (short)f2bf(c.x); v.y = (short)f2bf(c.y);
  v.z = (short)f2bf(c.z); v.w = (short)f2bf(c.w);
  *(s16x4*)(buf + s * stride + mt * 16 + q * 4) = v;
}

// C-layout (packed bf16 pairs p[8]) -> 2 MFMA B-frags. Verified in R4.
__device__ __forceinline__ void c2b_p(const uint p[8], bfrag8& b0, bfrag8& b1,
                                      int lane) {
  const int srcA = (lane & 15) | ((lane & 16) << 1);  // s + 32*(q&1)
  const int srcB = srcA + 16;
  const bool odd = (lane & 32) != 0;                  // q>=2 wants mt 1,3
  uint ev0 = p[0], ev1 = p[1], ev2 = p[4], ev3 = p[5];
  uint od0 = p[2], od1 = p[3], od2 = p[6], od3 = p[7];
  uint rA0, rA1, rA2, rA3, rB0, rB1, rB2, rB3;
  {
    uint e, o;
    e = (uint)__shfl((int)ev0, srcA); o = (uint)__shfl((int)od0, srcA); rA0 = odd ? o : e;
    e = (uint)__shfl((int)ev1, srcA); o = (uint)__shfl((int)od1, srcA); rA1 = odd ? o : e;
    e = (uint)__shfl((int)ev2, srcA); o = (uint)__shfl((int)od2, srcA); rA2 = odd ? o : e;
    e = (uint)__shfl((int)ev3, srcA); o = (uint)__shfl((int)od3, srcA); rA3 = odd ? o : e;
    e = (uint)__shfl((int)ev0, srcB); o = (uint)__shfl((int)od0, srcB); rB0 = odd ? o : e;
    e = (uint)__shfl((int)ev1, srcB); o = (uint)__shfl((int)od1, srcB); rB1 = odd ? o : e;
    e = (uint)__shfl((int)ev2, srcB); o = (uint)__shfl((int)od2, srcB); rB2 = odd ? o : e;
    e = (uint)__shfl((int)ev3, srcB); o = (uint)__shfl((int)od3, srcB); rB3 = odd ? o : e;
  }
  union U { uint u[4]; bfrag8 b; };
  U u0, u1;
  u0.u[0] = rA0; u0.u[1] = rA1; u0.u[2] = rB0; u0.u[3] = rB1;
  u1.u[0] = rA2; u1.u[1] = rA3; u1.u[2] = rB2; u1.u[3] = rB3;
  b0 = u0.b; b1 = u1.b;
}
__device__ __forceinline__ void c2b(const f32x4 c[4], bfrag8& b0, bfrag8& b1,
                                    int lane) {
  uint p[8];
#pragma unroll
  for (int mt = 0; mt < 4; ++mt) {
    p[2 * mt]     = pk2(c[mt].x, c[mt].y);
    p[2 * mt + 1] = pk2(c[mt].z, c[mt].w);
  }
  c2b_p(p, b0, b1, lane);
}

// c[mt] = W * X^T + bias; B from LDS (TH scratch, 64-wide).
template <int MT>
__device__ __forceinline__ void layerN(const short* in, const short* lw,
                                       int fbase, const float* bias, f32x4* c,
                                       int lane, int q, int s) {
  bfrag8 bf[2];
#pragma unroll
  for (int kt = 0; kt < 2; ++kt)
    bf[kt] = *(const bfrag8*)(in + s * S64 + kt * 32 + q * 8);
#pragma unroll
  for (int mt = 0; mt < MT; ++mt)
    c[mt] = *(const f32x4*)(bias + mt * 16 + q * 4);
#pragma unroll
  for (int mt = 0; mt < MT; ++mt) {
#pragma unroll
    for (int kt = 0; kt < 2; ++kt) {
      bfrag8 af = *(const bfrag8*)(lw + (fbase + mt * 2 + kt) * 512 + lane * 8);
      c[mt] = __builtin_amdgcn_mfma_f32_16x16x32_bf16(af, bf[kt], c[mt], 0, 0, 0);
    }
  }
}

// B from registers, KT k-tiles.
template <int MT, int KT>
__device__ __forceinline__ void layerBK(const bfrag8* bf, const short* lw,
                                        int fbase, const float* bias, f32x4* c,
                                        int lane, int q) {
#pragma unroll
  for (int mt = 0; mt < MT; ++mt)
    c[mt] = *(const f32x4*)(bias + mt * 16 + q * 4);
#pragma unroll
  for (int mt = 0; mt < MT; ++mt) {
#pragma unroll
    for (int kt = 0; kt < KT; ++kt) {
      bfrag8 af = *(const bfrag8*)(lw + (fbase + mt * KT + kt) * 512 + lane * 8);
      c[mt] = __builtin_amdgcn_mfma_f32_16x16x32_bf16(af, bf[kt], c[mt], 0, 0, 0);
    }
  }
}

// Two B inputs through the same weights: A-frag read once.
template <int MT>
__device__ __forceinline__ void layerB2(const bfrag8* bfA, const bfrag8* bfB,
                                        const short* lw, int fbase,
                                        const float* bias, f32x4* cA, f32x4* cB,
                                        int lane, int q) {
#pragma unroll
  for (int mt = 0; mt < MT; ++mt) {
    f32x4 b4 = *(const f32x4*)(bias + mt * 16 + q * 4);
    cA[mt] = b4; cB[mt] = b4;
  }
#pragma unroll
  for (int mt = 0; mt < MT; ++mt) {
#pragma unroll
    for (int kt = 0; kt < 2; ++kt) {
      bfrag8 af = *(const bfrag8*)(lw + (fbase + mt * 2 + kt) * 512 + lane * 8);
      cA[mt] = __builtin_amdgcn_mfma_f32_16x16x32_bf16(af, bfA[kt], cA[mt], 0, 0, 0);
      cB[mt] = __builtin_amdgcn_mfma_f32_16x16x32_bf16(af, bfB[kt], cB[mt], 0, 0, 0);
    }
  }
}

__device__ __forceinline__ void lnorm_c(f32x4 c[4], const float* g,
                                        const float* b, int q) {
  float sm = 0.f;
#pragma unroll
  for (int mt = 0; mt < 4; ++mt) sm += c[mt].x + c[mt].y + c[mt].z + c[mt].w;
  sm += __shfl_xor(sm, 16); sm += __shfl_xor(sm, 32);
  float mean = sm * (1.f / 64.f);
  float vs = 0.f;
#pragma unroll
  for (int mt = 0; mt < 4; ++mt) {
    f32x4 d = c[mt];
    d.x -= mean; d.y -= mean; d.z -= mean; d.w -= mean;
    c[mt] = d;
    vs += d.x * d.x + d.y * d.y + d.z * d.z + d.w * d.w;
  }
  vs += __shfl_xor(vs, 16); vs += __shfl_xor(vs, 32);
  float rs = rsqrtf(vs * (1.f / 64.f) + 1e-5f);
#pragma unroll
  for (int mt = 0; mt < 4; ++mt) {
    f32x4 g4 = *(const f32x4*)(g + mt * 16 + q * 4);
    f32x4 b4 = *(const f32x4*)(b + mt * 16 + q * 4);
    f32x4 v = c[mt];
    v.x = v.x * rs * g4.x + b4.x; v.y = v.y * rs * g4.y + b4.y;
    v.z = v.z * rs * g4.z + b4.z; v.w = v.w * rs * g4.w + b4.w;
    c[mt] = v;
  }
}

__device__ __forceinline__ float gelu1(float x) {
  float ax = fabsf(x) * 0.70710678118654752f;
  float t = __builtin_amdgcn_rcpf(1.0f + 0.3275911f * ax);
  float poly =
      ((((1.061405429f * t - 1.453152027f) * t + 1.421413741f) * t -
        0.284496736f) * t + 0.254829592f) * t;
  float e = __expf(-ax * ax);
  float erfv = copysignf(1.0f - poly * e, x);
  return 0.5f * x * (1.0f + erfv);
}

// ---------------------------------------------------------------------------
// prepack: weights -> A-frag bf16 order; params -> packed fp32 array
// ---------------------------------------------------------------------------
__global__ void prepack_kernel(Params p, ushort* wf) {
  int f = blockIdx.x;
  int lane = threadIdx.x;

  if (f == NFRAG) {
    float* pw = (float*)(wf + (size_t)NFRAG * 512);
    for (int t = lane; t < NPARAM; t += 64) {
      float v = 0.f;
      if      (t < 64)   v = p.b_in[t];
      else if (t < 128)  v = p.g_in[t - 64];
      else if (t < 192)  v = p.be_in[t - 128];
      else if (t < 384)  v = p.z_in_b[t - 192];
      else if (t < 448)  v = p.z_out_b[t - 384];
      else if (t < 576)  v = p.z_ffn_b1[t - 448];
      else if (t < 640)  v = p.z_ffn_b2[t - 576];
      else if (t < 704)  v = p.zn1_g[t - 640];
      else if (t < 768)  v = p.zn1_b[t - 704];
      else if (t < 832)  v = p.zn2_g[t - 768];
      else if (t < 896)  v = p.zn2_b[t - 832];
      else if (t < 960)  v = p.y_in_b[128 + t - 896];
      else if (t < 1024) v = p.y_out_b[t - 960];
      else if (t < 1152) v = p.y_ffn_b1[t - 1024];
      else if (t < 1216) v = p.y_ffn_b2[t - 1152];
      else if (t < 1280) v = p.yn1_g[t - 1216];
      else if (t < 1344) v = p.yn1_b[t - 1280];
      else if (t < 1408) v = p.yn2_g[t - 1344];
      else if (t < 1472) v = p.yn2_b[t - 1408];
      else if (t < 1536) v = p.W_out[t - 1472];
      else if (t == 1536) v = p.b_out[0];
      pw[t] = v;
    }
    return;
  }

  int q = lane >> 4, r = lane & 15;
  const float* src; int K, mt, kt, l;
  if (f < 28)        { src = p.W_in;                K = 200; mt = f / 7;  kt = f % 7; }
  else if (f < 36)   { l = f - 28;  src = p.z_in_w;            K = 64;  mt = l / 2; kt = l % 2; }
  else if (f < 44)   { l = f - 36;  src = p.z_in_w + 64 * 64;  K = 64;  mt = l / 2; kt = l % 2; }
  else if (f < 52)   { l = f - 44;  src = p.z_in_w + 128 * 64; K = 64;  mt = l / 2; kt = l % 2; }
  else if (f < 60)   { l = f - 52;  src = p.z_out_w;           K = 64;  mt = l / 2; kt = l % 2; }
  else if (f < 76)   { l = f - 60;  src = p.z_ffn_w1;          K = 64;  mt = l / 2; kt = l % 2; }
  else if (f < 92)   { l = f - 76;  src = p.z_ffn_w2;          K = 128; mt = l / 4; kt = l % 4; }
  else if (f < 100)  { l = f - 92;  src = p.y_in_w + 128 * 64; K = 64;  mt = l / 2; kt = l % 2; }
  else if (f < 108)  { l = f - 100; src = p.y_out_w;           K = 64;  mt = l / 2; kt = l % 2; }
  else if (f < 124)  { l = f - 108; src = p.y_ffn_w1;          K = 64;  mt = l / 2; kt = l % 2; }
  else               { l = f - 124; src = p.y_ffn_w2;          K = 128; mt = l / 4; kt = l % 4; }

  int row = mt * 16 + r;
  int col = kt * 32 + q * 8;
  bfrag8 o;
#pragma unroll
  for (int j = 0; j < 8; ++j) {
    int cc = col + j;
    float v = (cc < K) ? src[(size_t)row * K + cc] : 0.0f;
    o[j] = (short)f2bf(v);
  }
  *(bfrag8*)(wf + (size_t)f * 512 + lane * 8) = o;
}

// ---------------------------------------------------------------------------
// main kernel: 768 thr (12 waves), 1 block/CU, 3 waves/SIMD, weights in LDS.
// __launch_bounds__(768, 1): 12 waves / 4 EU = 3 waves/EU -> ~170-VGPR budget
// (structure proven to fit 128 spill-free in R6 -> zero spill here).
// ---------------------------------------------------------------------------
__global__ __launch_bounds__(BLK, 1)
void trm_mfma_kernel(Params p, const ushort* wf) {
  __shared__ __align__(16) short arena[ARENA_SH];
  const int tid = threadIdx.x;
  const int wave = tid >> 6, lane = tid & 63;
  const int q = lane >> 4, s = lane & 15;

  // ---- stage steady weights + params into LDS (once per block) ----
  {
    const uint4* srcw = (const uint4*)(wf + (size_t)28 * 512);
    uint4* dstw = (uint4*)(arena + L_W);
    for (int i = tid; i < NSTEADY * 64; i += BLK) dstw[i] = srcw[i];
    const uint4* srcp = (const uint4*)(wf + (size_t)NFRAG * 512);
    uint4* dstp = (uint4*)(arena + L_P);
    for (int i = tid; i < NPARAM / 4; i += BLK) dstp[i] = srcp[i];
  }
  __syncthreads();  // the only barrier

  const short* LW = arena + L_W;
  const float* P  = (const float*)(arena + L_P);
  short* TH = arena + L_ACT + wave * WAVE_SH;

  const int chunks = (p.nrows + ROWS_PB - 1) / ROWS_PB;
  for (int ic = blockIdx.x; ic < chunks; ic += gridDim.x) {
    const int row0 = ic * ROWS_PB + wave * 16;
    int row = row0 + s;
    if (row >= p.nrows) row = p.nrows - 1;

    // ---- x_proj = gelu(ln(x @ W_in^T + b_in)); stays in registers ----
    bfrag8 xpB[2];
    {
      const float* xr = p.x + (size_t)row * INDIM;
      bfrag8 xb[7];
#pragma unroll
      for (int kt = 0; kt < 7; ++kt) {
        int k0i = kt * 32 + q * 8;
        bfrag8 t;
        if (kt < 6 || q == 0) {
          f32x4 lo = *(const f32x4*)(xr + k0i);
          f32x4 hi = *(const f32x4*)(xr + k0i + 4);
          t[0] = (short)f2bf(lo.x); t[1] = (short)f2bf(lo.y);
          t[2] = (short)f2bf(lo.z); t[3] = (short)f2bf(lo.w);
          t[4] = (short)f2bf(hi.x); t[5] = (short)f2bf(hi.y);
          t[6] = (short)f2bf(hi.z); t[7] = (short)f2bf(hi.w);
        } else {
#pragma unroll
          for (int j = 0; j < 8; ++j) t[j] = 0;
        }
        xb[kt] = t;
      }
      f32x4 c[4];
#pragma unroll
      for (int mt = 0; mt < 4; ++mt)
        c[mt] = *(const f32x4*)(P + PB_BIN + mt * 16 + q * 4);
#pragma unroll
      for (int mt = 0; mt < 4; ++mt)
#pragma unroll
        for (int kt = 0; kt < 7; ++kt) {
          bfrag8 af =
              *(const bfrag8*)(wf + (size_t)(FB_WIN + mt * 7 + kt) * 512 + lane * 8);
          c[mt] = __builtin_amdgcn_mfma_f32_16x16x32_bf16(af, xb[kt], c[mt], 0, 0, 0);
        }
      lnorm_c(c, P + PB_GIN, P + PB_BEIN, q);
#pragma unroll
      for (int mt = 0; mt < 4; ++mt) {
        c[mt].x = gelu1(c[mt].x); c[mt].y = gelu1(c[mt].y);
        c[mt].z = gelu1(c[mt].z); c[mt].w = gelu1(c[mt].w);
      }
      c2b(c, xpB[0], xpB[1], lane);
    }

    // ---- k0/v0 packed bf16 in registers; zero state ----
    uint k0p[8], v0p[8], zCp[8], yCp[8];
    bfrag8 zB[2], yB[2];
    {
      f32x4 ck[4], cv[4];
      layerBK<4, 2>(xpB, LW, LB_ZK, P + PB_ZINB + 64, ck, lane, q);
      layerBK<4, 2>(xpB, LW, LB_ZV, P + PB_ZINB + 128, cv, lane, q);
#pragma unroll
      for (int mt = 0; mt < 4; ++mt) {
        k0p[2 * mt]     = pk2(ck[mt].x, ck[mt].y);
        k0p[2 * mt + 1] = pk2(ck[mt].z, ck[mt].w);
        v0p[2 * mt]     = pk2(cv[mt].x, cv[mt].y);
        v0p[2 * mt + 1] = pk2(cv[mt].z, cv[mt].w);
        zCp[2 * mt] = 0u; zCp[2 * mt + 1] = 0u;
        yCp[2 * mt] = 0u; yCp[2 * mt + 1] = 0u;
      }
#pragma unroll
      for (int kt = 0; kt < 2; ++kt) {
        bfrag8 t;
#pragma unroll
        for (int j = 0; j < 8; ++j) t[j] = 0;
        zB[kt] = t; yB[kt] = t;
      }
    }

    // ---- 16 recursive steps ----
    for (int st = 0; st < STEPS; ++st) {
      // -- attention k-phase: scores + softmax, k regs freed after --
      float w0[4], w1[4], w2[4], wi[4];
      {
        f32x4 q2[4], kz[4], ky[4];
        layerBK<4, 2>(zB, LW, LB_ZQ, P + PB_ZINB, q2, lane, q);
        layerB2<4>(zB, yB, LW, LB_ZK, P + PB_ZINB + 64, kz, ky, lane, q);
#pragma unroll
        for (int mt = 0; mt < 4; ++mt) {
          float a0 = q2[mt].x * upk_lo(k0p[2 * mt]) +
                     q2[mt].y * upk_hi(k0p[2 * mt]) +
                     q2[mt].z * upk_lo(k0p[2 * mt + 1]) +
                     q2[mt].w * upk_hi(k0p[2 * mt + 1]);
          float a1 = dot4(q2[mt], ky[mt]);
          float a2 = dot4(q2[mt], kz[mt]);
          a0 += __shfl_xor(a0, 16); a0 += __shfl_xor(a0, 32);
          a1 += __shfl_xor(a1, 16); a1 += __shfl_xor(a1, 32);
          a2 += __shfl_xor(a2, 16); a2 += __shfl_xor(a2, 32);
          a0 *= 0.25f; a1 *= 0.25f; a2 *= 0.25f;
          float mx = fmaxf(a0, fmaxf(a1, a2));
          float e0 = __expf(a0 - mx), e1 = __expf(a1 - mx), e2 = __expf(a2 - mx);
          w0[mt] = e0; w1[mt] = e1; w2[mt] = e2;
          wi[mt] = __builtin_amdgcn_rcpf(e0 + e1 + e2);
        }
      }
      // -- attention v-phase --
      {
        f32x4 vz[4], vy[4];
        layerB2<4>(zB, yB, LW, LB_ZV, P + PB_ZINB + 128, vz, vy, lane, q);
#pragma unroll
        for (int mt = 0; mt < 4; ++mt) {
          f32x4 o;
          o.x = (upk_lo(v0p[2 * mt])     * w0[mt] + vy[mt].x * w1[mt] +
                 vz[mt].x * w2[mt]) * wi[mt];
          o.y = (upk_hi(v0p[2 * mt])     * w0[mt] + vy[mt].y * w1[mt] +
                 vz[mt].y * w2[mt]) * wi[mt];
          o.z = (upk_lo(v0p[2 * mt + 1]) * w0[mt] + vy[mt].z * w1[mt] +
                 vz[mt].z * w2[mt]) * wi[mt];
          o.w = (upk_hi(v0p[2 * mt + 1]) * w0[mt] + vy[mt].w * w1[mt] +
                 vz[mt].w * w2[mt]) * wi[mt];
          stc(TH, S64, mt, q, s, o);
        }
      }

      // -- z branch --
      uint zrp[8];
      {
        f32x4 zr[4];
        layerN<4>(TH, LW, LB_ZOUT, P + PB_ZOUTB, zr, lane, q, s);
#pragma unroll
        for (int mt = 0; mt < 4; ++mt) {
          zr[mt].x += upk_lo(zCp[2 * mt]);     zr[mt].y += upk_hi(zCp[2 * mt]);
          zr[mt].z += upk_lo(zCp[2 * mt + 1]); zr[mt].w += upk_hi(zCp[2 * mt + 1]);
        }
        lnorm_c(zr, P + PB_ZN1G, P + PB_ZN1B, q);
#pragma unroll
        for (int mt = 0; mt < 4; ++mt) {
          stc(TH, S64, mt, q, s, zr[mt]);
          zrp[2 * mt]     = pk2(zr[mt].x, zr[mt].y);
          zrp[2 * mt + 1] = pk2(zr[mt].z, zr[mt].w);
        }
      }

      // z-FFN: two 4-tile halves, each gelu'd+packed+c2b'd before the next
      // (halves the h transient: peak live -16 VGPRs vs layerN<8>)
      bfrag8 hB[4];
#pragma unroll
      for (int g = 0; g < 2; ++g) {
        f32x4 h4[4];
        layerN<4>(TH, LW, LB_ZF1 + 8 * g, P + PB_ZF1B + 64 * g, h4, lane, q, s);
        uint ph[8];
#pragma unroll
        for (int mt = 0; mt < 4; ++mt) {
          h4[mt].x = gelu1(h4[mt].x); h4[mt].y = gelu1(h4[mt].y);
          h4[mt].z = gelu1(h4[mt].z); h4[mt].w = gelu1(h4[mt].w);
          ph[2 * mt]     = pk2(h4[mt].x, h4[mt].y);
          ph[2 * mt + 1] = pk2(h4[mt].z, h4[mt].w);
        }
        c2b_p(ph, hB[2 * g], hB[2 * g + 1], lane);
      }
      f32x4 z2[4];
      layerBK<4, 4>(hB, LW, LB_ZF2, P + PB_ZF2B, z2, lane, q);
#pragma unroll
      for (int mt = 0; mt < 4; ++mt) {
        z2[mt].x += upk_lo(zrp[2 * mt]);     z2[mt].y += upk_hi(zrp[2 * mt]);
        z2[mt].z += upk_lo(zrp[2 * mt + 1]); z2[mt].w += upk_hi(zrp[2 * mt + 1]);
      }
      lnorm_c(z2, P + PB_ZN2G, P + PB_ZN2B, q);
      {
        uint zp[8];
#pragma unroll
        for (int mt = 0; mt < 4; ++mt) {
          zp[2 * mt]     = pk2(z2[mt].x, z2[mt].y);
          zp[2 * mt + 1] = pk2(z2[mt].z, z2[mt].w);
          zCp[2 * mt] = zp[2 * mt]; zCp[2 * mt + 1] = zp[2 * mt + 1];
        }
        c2b_p(zp, zB[0], zB[1], lane);
      }

      // -- y branch --
      f32x4 t4[4];
      layerBK<4, 2>(zB, LW, LB_YV, P + PB_YVB, t4, lane, q);
#pragma unroll
      for (int mt = 0; mt < 4; ++mt) stc(TH, S64, mt, q, s, t4[mt]);

      uint yrp[8];
      {
        f32x4 yr[4];
        layerN<4>(TH, LW, LB_YOUT, P + PB_YOUTB, yr, lane, q, s);
#pragma unroll
        for (int mt = 0; mt < 4; ++mt) {
          yr[mt].x += upk_lo(yCp[2 * mt]);     yr[mt].y += upk_hi(yCp[2 * mt]);
          yr[mt].z += upk_lo(yCp[2 * mt + 1]); yr[mt].w += upk_hi(yCp[2 * mt + 1]);
        }
        lnorm_c(yr, P + PB_YN1G, P + PB_YN1B, q);
#pragma unroll
        for (int mt = 0; mt < 4; ++mt) {
          stc(TH, S64, mt, q, s, yr[mt]);
          yrp[2 * mt]     = pk2(yr[mt].x, yr[mt].y);
          yrp[2 * mt + 1] = pk2(yr[mt].z, yr[mt].w);
        }
      }

      // y-FFN: same split register-resident h path
#pragma unroll
      for (int g = 0; g < 2; ++g) {
        f32x4 h4[4];
        layerN<4>(TH, LW, LB_YF1 + 8 * g, P + PB_YF1B + 64 * g, h4, lane, q, s);
        uint ph[8];
#pragma unroll
        for (int mt = 0; mt < 4; ++mt) {
          h4[mt].x = gelu1(h4[mt].x); h4[mt].y = gelu1(h4[mt].y);
          h4[mt].z = gelu1(h4[mt].z); h4[mt].w = gelu1(h4[mt].w);
          ph[2 * mt]     = pk2(h4[mt].x, h4[mt].y);
          ph[2 * mt + 1] = pk2(h4[mt].z, h4[mt].w);
        }
        c2b_p(ph, hB[2 * g], hB[2 * g + 1], lane);
      }
      f32x4 y2[4];
      layerBK<4, 4>(hB, LW, LB_YF2, P + PB_YF2B, y2, lane, q);
#pragma unroll
      for (int mt = 0; mt < 4; ++mt) {
        y2[mt].x += upk_lo(yrp[2 * mt]);     y2[mt].y += upk_hi(yrp[2 * mt]);
        y2[mt].z += upk_lo(yrp[2 * mt + 1]); y2[mt].w += upk_hi(yrp[2 * mt + 1]);
      }
      lnorm_c(y2, P + PB_YN2G, P + PB_YN2B, q);
      {
        uint yp[8];
#pragma unroll
        for (int mt = 0; mt < 4; ++mt) {
          yp[2 * mt]     = pk2(y2[mt].x, y2[mt].y);
          yp[2 * mt + 1] = pk2(y2[mt].z, y2[mt].w);
          yCp[2 * mt] = yp[2 * mt]; yCp[2 * mt + 1] = yp[2 * mt + 1];
        }
        c2b_p(yp, yB[0], yB[1], lane);
      }
    }

    // ---- out = (y @ W_out^T + b_out)[:, 0] from packed carry ----
    float acc = 0.f;
#pragma unroll
    for (int mt = 0; mt < 4; ++mt) {
      f32x4 w4 = *(const f32x4*)(P + PB_WOUT + mt * 16 + q * 4);
      acc += upk_lo(yCp[2 * mt]) * w4.x + upk_hi(yCp[2 * mt]) * w4.y +
             upk_lo(yCp[2 * mt + 1]) * w4.z + upk_hi(yCp[2 * mt + 1]) * w4.w;
    }
    acc += __shfl_xor(acc, 16); acc += __shfl_xor(acc, 32);
    if (q == 0 && (row0 + s) < p.nrows) p.out[row0 + s] = acc + P[PB_BOUT];
  }
}

extern "C" void kernel_launch(void* const* d_in, const int* in_sizes, int n_in,
                              void* d_out, int out_size, void* d_ws,
                              size_t ws_size, hipStream_t stream) {
  Params p;
  const float* const* in = (const float* const*)d_in;
  p.x        = in[0];  p.W_in     = in[1];  p.b_in     = in[2];
  p.g_in     = in[3];  p.be_in    = in[4];
  p.z_in_w   = in[5];  p.z_in_b   = in[6];
  p.z_out_w  = in[7];  p.z_out_b  = in[8];
  p.z_ffn_w1 = in[9];  p.z_ffn_b1 = in[10];
  p.z_ffn_w2 = in[11]; p.z_ffn_b2 = in[12];
  p.zn1_g    = in[13]; p.zn1_b    = in[14];
  p.zn2_g    = in[15]; p.zn2_b    = in[16];
  p.y_in_w   = in[17]; p.y_in_b   = in[18];
  p.y_out_w  = in[19]; p.y_out_b  = in[20];
  p.y_ffn_w1 = in[21]; p.y_ffn_b1 = in[22];
  p.y_ffn_w2 = in[23]; p.y_ffn_b2 = in[24];
  p.yn1_g    = in[25]; p.yn1_b    = in[26];
  p.yn2_g    = in[27]; p.yn2_b    = in[28];
  p.W_out    = in[29]; p.b_out    = in[30];
  p.out      = (float*)d_out;
  p.nrows    = in_sizes[0] / INDIM;

  if (ws_size < (size_t)NFRAG * 1024 + NPARAM * 4) return;
  ushort* wf = (ushort*)d_ws;

  hipLaunchKernelGGL(prepack_kernel, dim3(NFRAG + 1), dim3(64), 0, stream, p, wf);
  int blocks = (p.nrows + ROWS_PB - 1) / ROWS_PB;   // 683 one-chunk blocks
  hipLaunchKernelGGL(trm_mfma_kernel, dim3(blocks), dim3(BLK), 0, stream, p, wf);
}

// Round 10
// 1025.093 us; speedup vs baseline: 1.0666x; 1.0666x over previous
//
#include <hip/hip_runtime.h>
#include <math.h>

// ---------------------------------------------------------------------------
// Round 10: dual-group waves — 1 wave = 32 samples (2 x 16-sample groups).
//   Every LDS A-frag read feeds 2 MFMAs (4 for shared z/y k/v layers):
//   A-frag + bias LDS traffic per sample halves, and each wave carries two
//   independent dependency chains (2x in-wave ILP) -> fixes both the ~55%
//   LDS-pipe load and the latency exposure that capped R6's 2-waves/SIMD.
//   512-thr blocks (8 waves), launch_bounds(512,1) -> 256-VGPR budget
//   (R3 precedent: allocator uses >128 under this bound). LDS 157.7 KB.
// ---------------------------------------------------------------------------

constexpr int STEPS = 16;
constexpr int INDIM = 200;

typedef __attribute__((ext_vector_type(8))) short bfrag8;   // 8 bf16 = 4 VGPR
typedef __attribute__((ext_vector_type(4))) float f32x4;
typedef __attribute__((ext_vector_type(4))) short s16x4;

constexpr int FB_WIN  = 0;
constexpr int NFRAG   = 140;
constexpr int NPARAM  = 1544;

// LDS-resident steady frag indices (= global index - 28)
constexpr int LB_ZQ   = 0;
constexpr int LB_ZK   = 8;
constexpr int LB_ZV   = 16;
constexpr int LB_ZOUT = 24;
constexpr int LB_ZF1  = 32;
constexpr int LB_ZF2  = 48;
constexpr int LB_YV   = 64;
constexpr int LB_YOUT = 72;
constexpr int LB_YF1  = 80;
constexpr int LB_YF2  = 96;
constexpr int NSTEADY = 112;

// packed param float offsets
constexpr int PB_BIN   = 0;
constexpr int PB_GIN   = 64;
constexpr int PB_BEIN  = 128;
constexpr int PB_ZINB  = 192;
constexpr int PB_ZOUTB = 384;
constexpr int PB_ZF1B  = 448;
constexpr int PB_ZF2B  = 576;
constexpr int PB_ZN1G  = 640;
constexpr int PB_ZN1B  = 704;
constexpr int PB_ZN2G  = 768;
constexpr int PB_ZN2B  = 832;
constexpr int PB_YVB   = 896;
constexpr int PB_YOUTB = 960;
constexpr int PB_YF1B  = 1024;
constexpr int PB_YF2B  = 1152;
constexpr int PB_YN1G  = 1216;
constexpr int PB_YN1B  = 1280;
constexpr int PB_YN2G  = 1344;
constexpr int PB_YN2B  = 1408;
constexpr int PB_WOUT  = 1472;
constexpr int PB_BOUT  = 1536;

// LDS arena layout (shorts)
constexpr int S64      = 72;
constexpr int L_W      = 0;                       // 112 frags = 57,344 shorts
constexpr int L_P      = 57344;                   // 3,088 shorts
constexpr int L_ACT    = 60432;                   // 8 waves x 2 TH buffers
constexpr int WAVE_SH  = 1152;                    // one TH: 16 x 72 shorts
constexpr int NWAVE    = 8;
constexpr int ARENA_SH = L_ACT + NWAVE * 2 * WAVE_SH; // 78,864 sh = 157,728 B

constexpr int BLK      = 512;                     // 8 waves
constexpr int ROWS_PB  = 256;                     // 8 waves x 32 rows

struct Params {
  const float *x, *W_in, *b_in, *g_in, *be_in;
  const float *z_in_w, *z_in_b, *z_out_w, *z_out_b;
  const float *z_ffn_w1, *z_ffn_b1, *z_ffn_w2, *z_ffn_b2;
  const float *zn1_g, *zn1_b, *zn2_g, *zn2_b;
  const float *y_in_w, *y_in_b, *y_out_w, *y_out_b;
  const float *y_ffn_w1, *y_ffn_b1, *y_ffn_w2, *y_ffn_b2;
  const float *yn1_g, *yn1_b, *yn2_g, *yn2_b;
  const float *W_out, *b_out;
  float *out;
  int nrows;
};

__device__ __forceinline__ ushort f2bf(float f) {
  uint u = __float_as_uint(f);
  u += 0x7FFFu + ((u >> 16) & 1u);
  return (ushort)(u >> 16);
}
__device__ __forceinline__ uint pk2(float a, float b) {
  return (uint)f2bf(a) | ((uint)f2bf(b) << 16);
}
__device__ __forceinline__ float upk_lo(uint u) {
  return __uint_as_float(u << 16);
}
__device__ __forceinline__ float upk_hi(uint u) {
  return __uint_as_float(u & 0xFFFF0000u);
}
__device__ __forceinline__ float dot4(f32x4 a, f32x4 b) {
  return a.x * b.x + a.y * b.y + a.z * b.z + a.w * b.w;
}
__device__ __forceinline__ void stc(short* buf, int mt, int q, int s, f32x4 c) {
  s16x4 v;
  v.x = (short)f2bf(c.x); v.y = (short)f2bf(c.y);
  v.z = (short)f2bf(c.z); v.w = (short)f2bf(c.w);
  *(s16x4*)(buf + s * S64 + mt * 16 + q * 4) = v;
}

// C-layout (packed bf16 pairs p[8]) -> 2 MFMA B-frags. Verified in R4.
__device__ __forceinline__ void c2b_p(const uint p[8], bfrag8& b0, bfrag8& b1,
                                      int lane) {
  const int srcA = (lane & 15) | ((lane & 16) << 1);
  const int srcB = srcA + 16;
  const bool odd = (lane & 32) != 0;
  uint ev0 = p[0], ev1 = p[1], ev2 = p[4], ev3 = p[5];
  uint od0 = p[2], od1 = p[3], od2 = p[6], od3 = p[7];
  uint rA0, rA1, rA2, rA3, rB0, rB1, rB2, rB3;
  {
    uint e, o;
    e = (uint)__shfl((int)ev0, srcA); o = (uint)__shfl((int)od0, srcA); rA0 = odd ? o : e;
    e = (uint)__shfl((int)ev1, srcA); o = (uint)__shfl((int)od1, srcA); rA1 = odd ? o : e;
    e = (uint)__shfl((int)ev2, srcA); o = (uint)__shfl((int)od2, srcA); rA2 = odd ? o : e;
    e = (uint)__shfl((int)ev3, srcA); o = (uint)__shfl((int)od3, srcA); rA3 = odd ? o : e;
    e = (uint)__shfl((int)ev0, srcB); o = (uint)__shfl((int)od0, srcB); rB0 = odd ? o : e;
    e = (uint)__shfl((int)ev1, srcB); o = (uint)__shfl((int)od1, srcB); rB1 = odd ? o : e;
    e = (uint)__shfl((int)ev2, srcB); o = (uint)__shfl((int)od2, srcB); rB2 = odd ? o : e;
    e = (uint)__shfl((int)ev3, srcB); o = (uint)__shfl((int)od3, srcB); rB3 = odd ? o : e;
  }
  union U { uint u[4]; bfrag8 b; };
  U u0, u1;
  u0.u[0] = rA0; u0.u[1] = rA1; u0.u[2] = rB0; u0.u[3] = rB1;
  u1.u[0] = rA2; u1.u[1] = rA3; u1.u[2] = rB2; u1.u[3] = rB3;
  b0 = u0.b; b1 = u1.b;
}
__device__ __forceinline__ void c2b(const f32x4 c[4], bfrag8& b0, bfrag8& b1,
                                    int lane) {
  uint p[8];
#pragma unroll
  for (int mt = 0; mt < 4; ++mt) {
    p[2 * mt]     = pk2(c[mt].x, c[mt].y);
    p[2 * mt + 1] = pk2(c[mt].z, c[mt].w);
  }
  c2b_p(p, b0, b1, lane);
}

// Two register-B inputs (one per group) through same weights: A-frag read once.
template <int MT, int KT>
__device__ __forceinline__ void layerG2(const bfrag8* bfA, const bfrag8* bfB,
                                        const short* lw, int fbase,
                                        const float* bias, f32x4* cA, f32x4* cB,
                                        int lane, int q) {
#pragma unroll
  for (int mt = 0; mt < MT; ++mt) {
    f32x4 b4 = *(const f32x4*)(bias + mt * 16 + q * 4);
    cA[mt] = b4; cB[mt] = b4;
  }
#pragma unroll
  for (int mt = 0; mt < MT; ++mt) {
#pragma unroll
    for (int kt = 0; kt < KT; ++kt) {
      bfrag8 af = *(const bfrag8*)(lw + (fbase + mt * KT + kt) * 512 + lane * 8);
      cA[mt] = __builtin_amdgcn_mfma_f32_16x16x32_bf16(af, bfA[kt], cA[mt], 0, 0, 0);
      cB[mt] = __builtin_amdgcn_mfma_f32_16x16x32_bf16(af, bfB[kt], cB[mt], 0, 0, 0);
    }
  }
}

// Four register-B inputs (z/y tokens x 2 groups) through same weights.
template <int MT>
__device__ __forceinline__ void layerG4(const bfrag8* z0, const bfrag8* y0,
                                        const bfrag8* z1, const bfrag8* y1,
                                        const short* lw, int fbase,
                                        const float* bias,
                                        f32x4* cz0, f32x4* cy0,
                                        f32x4* cz1, f32x4* cy1,
                                        int lane, int q) {
#pragma unroll
  for (int mt = 0; mt < MT; ++mt) {
    f32x4 b4 = *(const f32x4*)(bias + mt * 16 + q * 4);
    cz0[mt] = b4; cy0[mt] = b4; cz1[mt] = b4; cy1[mt] = b4;
  }
#pragma unroll
  for (int mt = 0; mt < MT; ++mt) {
#pragma unroll
    for (int kt = 0; kt < 2; ++kt) {
      bfrag8 af = *(const bfrag8*)(lw + (fbase + mt * 2 + kt) * 512 + lane * 8);
      cz0[mt] = __builtin_amdgcn_mfma_f32_16x16x32_bf16(af, z0[kt], cz0[mt], 0, 0, 0);
      cy0[mt] = __builtin_amdgcn_mfma_f32_16x16x32_bf16(af, y0[kt], cy0[mt], 0, 0, 0);
      cz1[mt] = __builtin_amdgcn_mfma_f32_16x16x32_bf16(af, z1[kt], cz1[mt], 0, 0, 0);
      cy1[mt] = __builtin_amdgcn_mfma_f32_16x16x32_bf16(af, y1[kt], cy1[mt], 0, 0, 0);
    }
  }
}

// Dual-group TH-based layer: B-frags from both groups' TH; A-frag read once.
template <int MT>
__device__ __forceinline__ void layerTHG2(const short* t0, const short* t1,
                                          const short* lw, int fbase,
                                          const float* bias, f32x4* c0,
                                          f32x4* c1, int lane, int q, int s) {
  bfrag8 b0[2], b1[2];
#pragma unroll
  for (int kt = 0; kt < 2; ++kt) {
    b0[kt] = *(const bfrag8*)(t0 + s * S64 + kt * 32 + q * 8);
    b1[kt] = *(const bfrag8*)(t1 + s * S64 + kt * 32 + q * 8);
  }
#pragma unroll
  for (int mt = 0; mt < MT; ++mt) {
    f32x4 b4 = *(const f32x4*)(bias + mt * 16 + q * 4);
    c0[mt] = b4; c1[mt] = b4;
  }
#pragma unroll
  for (int mt = 0; mt < MT; ++mt) {
#pragma unroll
    for (int kt = 0; kt < 2; ++kt) {
      bfrag8 af = *(const bfrag8*)(lw + (fbase + mt * 2 + kt) * 512 + lane * 8);
      c0[mt] = __builtin_amdgcn_mfma_f32_16x16x32_bf16(af, b0[kt], c0[mt], 0, 0, 0);
      c1[mt] = __builtin_amdgcn_mfma_f32_16x16x32_bf16(af, b1[kt], c1[mt], 0, 0, 0);
    }
  }
}

__device__ __forceinline__ void lnorm_c(f32x4 c[4], const float* g,
                                        const float* b, int q) {
  float sm = 0.f;
#pragma unroll
  for (int mt = 0; mt < 4; ++mt) sm += c[mt].x + c[mt].y + c[mt].z + c[mt].w;
  sm += __shfl_xor(sm, 16); sm += __shfl_xor(sm, 32);
  float mean = sm * (1.f / 64.f);
  float vs = 0.f;
#pragma unroll
  for (int mt = 0; mt < 4; ++mt) {
    f32x4 d = c[mt];
    d.x -= mean; d.y -= mean; d.z -= mean; d.w -= mean;
    c[mt] = d;
    vs += d.x * d.x + d.y * d.y + d.z * d.z + d.w * d.w;
  }
  vs += __shfl_xor(vs, 16); vs += __shfl_xor(vs, 32);
  float rs = rsqrtf(vs * (1.f / 64.f) + 1e-5f);
#pragma unroll
  for (int mt = 0; mt < 4; ++mt) {
    f32x4 g4 = *(const f32x4*)(g + mt * 16 + q * 4);
    f32x4 b4 = *(const f32x4*)(b + mt * 16 + q * 4);
    f32x4 v = c[mt];
    v.x = v.x * rs * g4.x + b4.x; v.y = v.y * rs * g4.y + b4.y;
    v.z = v.z * rs * g4.z + b4.z; v.w = v.w * rs * g4.w + b4.w;
    c[mt] = v;
  }
}

__device__ __forceinline__ float gelu1(float x) {
  float ax = fabsf(x) * 0.70710678118654752f;
  float t = __builtin_amdgcn_rcpf(1.0f + 0.3275911f * ax);
  float poly =
      ((((1.061405429f * t - 1.453152027f) * t + 1.421413741f) * t -
        0.284496736f) * t + 0.254829592f) * t;
  float e = __expf(-ax * ax);
  float erfv = copysignf(1.0f - poly * e, x);
  return 0.5f * x * (1.0f + erfv);
}

// ---------------------------------------------------------------------------
// prepack: weights -> A-frag bf16 order; params -> packed fp32 array
// ---------------------------------------------------------------------------
__global__ void prepack_kernel(Params p, ushort* wf) {
  int f = blockIdx.x;
  int lane = threadIdx.x;

  if (f == NFRAG) {
    float* pw = (float*)(wf + (size_t)NFRAG * 512);
    for (int t = lane; t < NPARAM; t += 64) {
      float v = 0.f;
      if      (t < 64)   v = p.b_in[t];
      else if (t < 128)  v = p.g_in[t - 64];
      else if (t < 192)  v = p.be_in[t - 128];
      else if (t < 384)  v = p.z_in_b[t - 192];
      else if (t < 448)  v = p.z_out_b[t - 384];
      else if (t < 576)  v = p.z_ffn_b1[t - 448];
      else if (t < 640)  v = p.z_ffn_b2[t - 576];
      else if (t < 704)  v = p.zn1_g[t - 640];
      else if (t < 768)  v = p.zn1_b[t - 704];
      else if (t < 832)  v = p.zn2_g[t - 768];
      else if (t < 896)  v = p.zn2_b[t - 832];
      else if (t < 960)  v = p.y_in_b[128 + t - 896];
      else if (t < 1024) v = p.y_out_b[t - 960];
      else if (t < 1152) v = p.y_ffn_b1[t - 1024];
      else if (t < 1216) v = p.y_ffn_b2[t - 1152];
      else if (t < 1280) v = p.yn1_g[t - 1216];
      else if (t < 1344) v = p.yn1_b[t - 1280];
      else if (t < 1408) v = p.yn2_g[t - 1344];
      else if (t < 1472) v = p.yn2_b[t - 1408];
      else if (t < 1536) v = p.W_out[t - 1472];
      else if (t == 1536) v = p.b_out[0];
      pw[t] = v;
    }
    return;
  }

  int q = lane >> 4, r = lane & 15;
  const float* src; int K, mt, kt, l;
  if (f < 28)        { src = p.W_in;                K = 200; mt = f / 7;  kt = f % 7; }
  else if (f < 36)   { l = f - 28;  src = p.z_in_w;            K = 64;  mt = l / 2; kt = l % 2; }
  else if (f < 44)   { l = f - 36;  src = p.z_in_w + 64 * 64;  K = 64;  mt = l / 2; kt = l % 2; }
  else if (f < 52)   { l = f - 44;  src = p.z_in_w + 128 * 64; K = 64;  mt = l / 2; kt = l % 2; }
  else if (f < 60)   { l = f - 52;  src = p.z_out_w;           K = 64;  mt = l / 2; kt = l % 2; }
  else if (f < 76)   { l = f - 60;  src = p.z_ffn_w1;          K = 64;  mt = l / 2; kt = l % 2; }
  else if (f < 92)   { l = f - 76;  src = p.z_ffn_w2;          K = 128; mt = l / 4; kt = l % 4; }
  else if (f < 100)  { l = f - 92;  src = p.y_in_w + 128 * 64; K = 64;  mt = l / 2; kt = l % 2; }
  else if (f < 108)  { l = f - 100; src = p.y_out_w;           K = 64;  mt = l / 2; kt = l % 2; }
  else if (f < 124)  { l = f - 108; src = p.y_ffn_w1;          K = 64;  mt = l / 2; kt = l % 2; }
  else               { l = f - 124; src = p.y_ffn_w2;          K = 128; mt = l / 4; kt = l % 4; }

  int row = mt * 16 + r;
  int col = kt * 32 + q * 8;
  bfrag8 o;
#pragma unroll
  for (int j = 0; j < 8; ++j) {
    int cc = col + j;
    float v = (cc < K) ? src[(size_t)row * K + cc] : 0.0f;
    o[j] = (short)f2bf(v);
  }
  *(bfrag8*)(wf + (size_t)f * 512 + lane * 8) = o;
}

// ---------------------------------------------------------------------------
// main kernel: 512 thr (8 waves), 1 block/CU, each wave = 32 samples (2 groups)
// ---------------------------------------------------------------------------
__global__ __launch_bounds__(BLK, 1)
void trm_mfma_kernel(Params p, const ushort* wf) {
  __shared__ __align__(16) short arena[ARENA_SH];
  const int tid = threadIdx.x;
  const int wave = tid >> 6, lane = tid & 63;
  const int q = lane >> 4, s = lane & 15;

  // ---- stage steady weights + params into LDS (once per block) ----
  {
    const uint4* srcw = (const uint4*)(wf + (size_t)28 * 512);
    uint4* dstw = (uint4*)(arena + L_W);
    for (int i = tid; i < NSTEADY * 64; i += BLK) dstw[i] = srcw[i];
    const uint4* srcp = (const uint4*)(wf + (size_t)NFRAG * 512);
    uint4* dstp = (uint4*)(arena + L_P);
    for (int i = tid; i < NPARAM / 4; i += BLK) dstp[i] = srcp[i];
  }
  __syncthreads();  // the only barrier

  const short* LW = arena + L_W;
  const float* P  = (const float*)(arena + L_P);
  short* TH0 = arena + L_ACT + wave * (2 * WAVE_SH);
  short* TH1 = TH0 + WAVE_SH;

  const int chunks = (p.nrows + ROWS_PB - 1) / ROWS_PB;
  for (int ic = blockIdx.x; ic < chunks; ic += gridDim.x) {
    const int base = ic * ROWS_PB + wave * 32;

    // ---- x_proj per group (prologue; sequential, negligible) ----
    bfrag8 xpB[2][2];
#pragma unroll
    for (int g = 0; g < 2; ++g) {
      int row = base + g * 16 + s;
      if (row >= p.nrows) row = p.nrows - 1;
      const float* xr = p.x + (size_t)row * INDIM;
      bfrag8 xb[7];
#pragma unroll
      for (int kt = 0; kt < 7; ++kt) {
        int k0i = kt * 32 + q * 8;
        bfrag8 t;
        if (kt < 6 || q == 0) {
          f32x4 lo = *(const f32x4*)(xr + k0i);
          f32x4 hi = *(const f32x4*)(xr + k0i + 4);
          t[0] = (short)f2bf(lo.x); t[1] = (short)f2bf(lo.y);
          t[2] = (short)f2bf(lo.z); t[3] = (short)f2bf(lo.w);
          t[4] = (short)f2bf(hi.x); t[5] = (short)f2bf(hi.y);
          t[6] = (short)f2bf(hi.z); t[7] = (short)f2bf(hi.w);
        } else {
#pragma unroll
          for (int j = 0; j < 8; ++j) t[j] = 0;
        }
        xb[kt] = t;
      }
      f32x4 c[4];
#pragma unroll
      for (int mt = 0; mt < 4; ++mt)
        c[mt] = *(const f32x4*)(P + PB_BIN + mt * 16 + q * 4);
#pragma unroll
      for (int mt = 0; mt < 4; ++mt)
#pragma unroll
        for (int kt = 0; kt < 7; ++kt) {
          bfrag8 af =
              *(const bfrag8*)(wf + (size_t)(FB_WIN + mt * 7 + kt) * 512 + lane * 8);
          c[mt] = __builtin_amdgcn_mfma_f32_16x16x32_bf16(af, xb[kt], c[mt], 0, 0, 0);
        }
      lnorm_c(c, P + PB_GIN, P + PB_BEIN, q);
#pragma unroll
      for (int mt = 0; mt < 4; ++mt) {
        c[mt].x = gelu1(c[mt].x); c[mt].y = gelu1(c[mt].y);
        c[mt].z = gelu1(c[mt].z); c[mt].w = gelu1(c[mt].w);
      }
      c2b(c, xpB[g][0], xpB[g][1], lane);
    }

    // ---- k0/v0 (shared A-frags across groups); zero state ----
    uint k0p[2][8], v0p[2][8], zCp[2][8], yCp[2][8];
    bfrag8 zB[2][2], yB[2][2];
    {
      f32x4 ck[2][4];
      layerG2<4, 2>(xpB[0], xpB[1], LW, LB_ZK, P + PB_ZINB + 64, ck[0], ck[1],
                    lane, q);
#pragma unroll
      for (int g = 0; g < 2; ++g)
#pragma unroll
        for (int mt = 0; mt < 4; ++mt) {
          k0p[g][2 * mt]     = pk2(ck[g][mt].x, ck[g][mt].y);
          k0p[g][2 * mt + 1] = pk2(ck[g][mt].z, ck[g][mt].w);
        }
      f32x4 cv[2][4];
      layerG2<4, 2>(xpB[0], xpB[1], LW, LB_ZV, P + PB_ZINB + 128, cv[0], cv[1],
                    lane, q);
#pragma unroll
      for (int g = 0; g < 2; ++g)
#pragma unroll
        for (int mt = 0; mt < 4; ++mt) {
          v0p[g][2 * mt]     = pk2(cv[g][mt].x, cv[g][mt].y);
          v0p[g][2 * mt + 1] = pk2(cv[g][mt].z, cv[g][mt].w);
          zCp[g][2 * mt] = 0u; zCp[g][2 * mt + 1] = 0u;
          yCp[g][2 * mt] = 0u; yCp[g][2 * mt + 1] = 0u;
        }
#pragma unroll
      for (int g = 0; g < 2; ++g)
#pragma unroll
        for (int kt = 0; kt < 2; ++kt) {
          bfrag8 t;
#pragma unroll
          for (int j = 0; j < 8; ++j) t[j] = 0;
          zB[g][kt] = t; yB[g][kt] = t;
        }
    }

    // ---- 16 recursive steps ----
    for (int st = 0; st < STEPS; ++st) {
      // -- attention k-phase --
      float w0[2][4], w1[2][4], w2[2][4], wi[2][4];
      {
        f32x4 q2[2][4];
        layerG2<4, 2>(zB[0], zB[1], LW, LB_ZQ, P + PB_ZINB, q2[0], q2[1],
                      lane, q);
        f32x4 kz[2][4], ky[2][4];
        layerG4<4>(zB[0], yB[0], zB[1], yB[1], LW, LB_ZK, P + PB_ZINB + 64,
                   kz[0], ky[0], kz[1], ky[1], lane, q);
#pragma unroll
        for (int g = 0; g < 2; ++g)
#pragma unroll
          for (int mt = 0; mt < 4; ++mt) {
            float a0 = q2[g][mt].x * upk_lo(k0p[g][2 * mt]) +
                       q2[g][mt].y * upk_hi(k0p[g][2 * mt]) +
                       q2[g][mt].z * upk_lo(k0p[g][2 * mt + 1]) +
                       q2[g][mt].w * upk_hi(k0p[g][2 * mt + 1]);
            float a1 = dot4(q2[g][mt], ky[g][mt]);
            float a2 = dot4(q2[g][mt], kz[g][mt]);
            a0 += __shfl_xor(a0, 16); a0 += __shfl_xor(a0, 32);
            a1 += __shfl_xor(a1, 16); a1 += __shfl_xor(a1, 32);
            a2 += __shfl_xor(a2, 16); a2 += __shfl_xor(a2, 32);
            a0 *= 0.25f; a1 *= 0.25f; a2 *= 0.25f;
            float mx = fmaxf(a0, fmaxf(a1, a2));
            float e0 = __expf(a0 - mx), e1 = __expf(a1 - mx), e2 = __expf(a2 - mx);
            w0[g][mt] = e0; w1[g][mt] = e1; w2[g][mt] = e2;
            wi[g][mt] = __builtin_amdgcn_rcpf(e0 + e1 + e2);
          }
      }
      // -- attention v-phase --
      {
        f32x4 vz[2][4], vy[2][4];
        layerG4<4>(zB[0], yB[0], zB[1], yB[1], LW, LB_ZV, P + PB_ZINB + 128,
                   vz[0], vy[0], vz[1], vy[1], lane, q);
#pragma unroll
        for (int g = 0; g < 2; ++g) {
          short* TH = g ? TH1 : TH0;
#pragma unroll
          for (int mt = 0; mt < 4; ++mt) {
            f32x4 o;
            o.x = (upk_lo(v0p[g][2 * mt])     * w0[g][mt] + vy[g][mt].x * w1[g][mt] +
                   vz[g][mt].x * w2[g][mt]) * wi[g][mt];
            o.y = (upk_hi(v0p[g][2 * mt])     * w0[g][mt] + vy[g][mt].y * w1[g][mt] +
                   vz[g][mt].y * w2[g][mt]) * wi[g][mt];
            o.z = (upk_lo(v0p[g][2 * mt + 1]) * w0[g][mt] + vy[g][mt].z * w1[g][mt] +
                   vz[g][mt].z * w2[g][mt]) * wi[g][mt];
            o.w = (upk_hi(v0p[g][2 * mt + 1]) * w0[g][mt] + vy[g][mt].w * w1[g][mt] +
                   vz[g][mt].w * w2[g][mt]) * wi[g][mt];
            stc(TH, mt, q, s, o);
          }
        }
      }

      // -- z branch --
      uint zrp[2][8];
      {
        f32x4 zr[2][4];
        layerTHG2<4>(TH0, TH1, LW, LB_ZOUT, P + PB_ZOUTB, zr[0], zr[1],
                     lane, q, s);
#pragma unroll
        for (int g = 0; g < 2; ++g) {
          short* TH = g ? TH1 : TH0;
#pragma unroll
          for (int mt = 0; mt < 4; ++mt) {
            zr[g][mt].x += upk_lo(zCp[g][2 * mt]);
            zr[g][mt].y += upk_hi(zCp[g][2 * mt]);
            zr[g][mt].z += upk_lo(zCp[g][2 * mt + 1]);
            zr[g][mt].w += upk_hi(zCp[g][2 * mt + 1]);
          }
          lnorm_c(zr[g], P + PB_ZN1G, P + PB_ZN1B, q);
#pragma unroll
          for (int mt = 0; mt < 4; ++mt) {
            stc(TH, mt, q, s, zr[g][mt]);
            zrp[g][2 * mt]     = pk2(zr[g][mt].x, zr[g][mt].y);
            zrp[g][2 * mt + 1] = pk2(zr[g][mt].z, zr[g][mt].w);
          }
        }
      }

      // z-FFN: two 4-tile halves; h in regs -> c2b; A-frags shared
      bfrag8 hB[2][4];
#pragma unroll
      for (int gh = 0; gh < 2; ++gh) {
        f32x4 h4[2][4];
        layerTHG2<4>(TH0, TH1, LW, LB_ZF1 + 8 * gh, P + PB_ZF1B + 64 * gh,
                     h4[0], h4[1], lane, q, s);
#pragma unroll
        for (int g = 0; g < 2; ++g) {
          uint ph[8];
#pragma unroll
          for (int mt = 0; mt < 4; ++mt) {
            h4[g][mt].x = gelu1(h4[g][mt].x); h4[g][mt].y = gelu1(h4[g][mt].y);
            h4[g][mt].z = gelu1(h4[g][mt].z); h4[g][mt].w = gelu1(h4[g][mt].w);
            ph[2 * mt]     = pk2(h4[g][mt].x, h4[g][mt].y);
            ph[2 * mt + 1] = pk2(h4[g][mt].z, h4[g][mt].w);
          }
          c2b_p(ph, hB[g][2 * gh], hB[g][2 * gh + 1], lane);
        }
      }
      {
        f32x4 z2[2][4];
        layerG2<4, 4>(hB[0], hB[1], LW, LB_ZF2, P + PB_ZF2B, z2[0], z2[1],
                      lane, q);
#pragma unroll
        for (int g = 0; g < 2; ++g) {
#pragma unroll
          for (int mt = 0; mt < 4; ++mt) {
            z2[g][mt].x += upk_lo(zrp[g][2 * mt]);
            z2[g][mt].y += upk_hi(zrp[g][2 * mt]);
            z2[g][mt].z += upk_lo(zrp[g][2 * mt + 1]);
            z2[g][mt].w += upk_hi(zrp[g][2 * mt + 1]);
          }
          lnorm_c(z2[g], P + PB_ZN2G, P + PB_ZN2B, q);
          uint zp[8];
#pragma unroll
          for (int mt = 0; mt < 4; ++mt) {
            zp[2 * mt]     = pk2(z2[g][mt].x, z2[g][mt].y);
            zp[2 * mt + 1] = pk2(z2[g][mt].z, z2[g][mt].w);
            zCp[g][2 * mt] = zp[2 * mt]; zCp[g][2 * mt + 1] = zp[2 * mt + 1];
          }
          c2b_p(zp, zB[g][0], zB[g][1], lane);
        }
      }

      // -- y branch --
      {
        f32x4 t4[2][4];
        layerG2<4, 2>(zB[0], zB[1], LW, LB_YV, P + PB_YVB, t4[0], t4[1],
                      lane, q);
#pragma unroll
        for (int g = 0; g < 2; ++g) {
          short* TH = g ? TH1 : TH0;
#pragma unroll
          for (int mt = 0; mt < 4; ++mt) stc(TH, mt, q, s, t4[g][mt]);
        }
      }

      uint yrp[2][8];
      {
        f32x4 yr[2][4];
        layerTHG2<4>(TH0, TH1, LW, LB_YOUT, P + PB_YOUTB, yr[0], yr[1],
                     lane, q, s);
#pragma unroll
        for (int g = 0; g < 2; ++g) {
          short* TH = g ? TH1 : TH0;
#pragma unroll
          for (int mt = 0; mt < 4; ++mt) {
            yr[g][mt].x += upk_lo(yCp[g][2 * mt]);
            yr[g][mt].y += upk_hi(yCp[g][2 * mt]);
            yr[g][mt].z += upk_lo(yCp[g][2 * mt + 1]);
            yr[g][mt].w += upk_hi(yCp[g][2 * mt + 1]);
          }
          lnorm_c(yr[g], P + PB_YN1G, P + PB_YN1B, q);
#pragma unroll
          for (int mt = 0; mt < 4; ++mt) {
            stc(TH, mt, q, s, yr[g][mt]);
            yrp[g][2 * mt]     = pk2(yr[g][mt].x, yr[g][mt].y);
            yrp[g][2 * mt + 1] = pk2(yr[g][mt].z, yr[g][mt].w);
          }
        }
      }

      // y-FFN
#pragma unroll
      for (int gh = 0; gh < 2; ++gh) {
        f32x4 h4[2][4];
        layerTHG2<4>(TH0, TH1, LW, LB_YF1 + 8 * gh, P + PB_YF1B + 64 * gh,
                     h4[0], h4[1], lane, q, s);
#pragma unroll
        for (int g = 0; g < 2; ++g) {
          uint ph[8];
#pragma unroll
          for (int mt = 0; mt < 4; ++mt) {
            h4[g][mt].x = gelu1(h4[g][mt].x); h4[g][mt].y = gelu1(h4[g][mt].y);
            h4[g][mt].z = gelu1(h4[g][mt].z); h4[g][mt].w = gelu1(h4[g][mt].w);
            ph[2 * mt]     = pk2(h4[g][mt].x, h4[g][mt].y);
            ph[2 * mt + 1] = pk2(h4[g][mt].z, h4[g][mt].w);
          }
          c2b_p(ph, hB[g][2 * gh], hB[g][2 * gh + 1], lane);
        }
      }
      {
        f32x4 y2[2][4];
        layerG2<4, 4>(hB[0], hB[1], LW, LB_YF2, P + PB_YF2B, y2[0], y2[1],
                      lane, q);
#pragma unroll
        for (int g = 0; g < 2; ++g) {
#pragma unroll
          for (int mt = 0; mt < 4; ++mt) {
            y2[g][mt].x += upk_lo(yrp[g][2 * mt]);
            y2[g][mt].y += upk_hi(yrp[g][2 * mt]);
            y2[g][mt].z += upk_lo(yrp[g][2 * mt + 1]);
            y2[g][mt].w += upk_hi(yrp[g][2 * mt + 1]);
          }
          lnorm_c(y2[g], P + PB_YN2G, P + PB_YN2B, q);
          uint yp[8];
#pragma unroll
          for (int mt = 0; mt < 4; ++mt) {
            yp[2 * mt]     = pk2(y2[g][mt].x, y2[g][mt].y);
            yp[2 * mt + 1] = pk2(y2[g][mt].z, y2[g][mt].w);
            yCp[g][2 * mt] = yp[2 * mt]; yCp[g][2 * mt + 1] = yp[2 * mt + 1];
          }
          c2b_p(yp, yB[g][0], yB[g][1], lane);
        }
      }
    }

    // ---- out = (y @ W_out^T + b_out)[:, 0] per group ----
#pragma unroll
    for (int g = 0; g < 2; ++g) {
      float acc = 0.f;
#pragma unroll
      for (int mt = 0; mt < 4; ++mt) {
        f32x4 w4 = *(const f32x4*)(P + PB_WOUT + mt * 16 + q * 4);
        acc += upk_lo(yCp[g][2 * mt]) * w4.x + upk_hi(yCp[g][2 * mt]) * w4.y +
               upk_lo(yCp[g][2 * mt + 1]) * w4.z +
               upk_hi(yCp[g][2 * mt + 1]) * w4.w;
      }
      acc += __shfl_xor(acc, 16); acc += __shfl_xor(acc, 32);
      int orow = base + g * 16 + s;
      if (q == 0 && orow < p.nrows) p.out[orow] = acc + P[PB_BOUT];
    }
  }
}

extern "C" void kernel_launch(void* const* d_in, const int* in_sizes, int n_in,
                              void* d_out, int out_size, void* d_ws,
                              size_t ws_size, hipStream_t stream) {
  Params p;
  const float* const* in = (const float* const*)d_in;
  p.x        = in[0];  p.W_in     = in[1];  p.b_in     = in[2];
  p.g_in     = in[3];  p.be_in    = in[4];
  p.z_in_w   = in[5];  p.z_in_b   = in[6];
  p.z_out_w  = in[7];  p.z_out_b  = in[8];
  p.z_ffn_w1 = in[9];  p.z_ffn_b1 = in[10];
  p.z_ffn_w2 = in[11]; p.z_ffn_b2 = in[12];
  p.zn1_g    = in[13]; p.zn1_b    = in[14];
  p.zn2_g    = in[15]; p.zn2_b    = in[16];
  p.y_in_w   = in[17]; p.y_in_b   = in[18];
  p.y_out_w  = in[19]; p.y_out_b  = in[20];
  p.y_ffn_w1 = in[21]; p.y_ffn_b1 = in[22];
  p.y_ffn_w2 = in[23]; p.y_ffn_b2 = in[24];
  p.yn1_g    = in[25]; p.yn1_b    = in[26];
  p.yn2_g    = in[27]; p.yn2_b    = in[28];
  p.W_out    = in[29]; p.b_out    = in[30];
  p.out      = (float*)d_out;
  p.nrows    = in_sizes[0] / INDIM;

  if (ws_size < (size_t)NFRAG * 1024 + NPARAM * 4) return;
  ushort* wf = (ushort*)d_ws;

  hipLaunchKernelGGL(prepack_kernel, dim3(NFRAG + 1), dim3(64), 0, stream, p, wf);
  int blocks = (p.nrows + ROWS_PB - 1) / ROWS_PB;   // 512 blocks
  hipLaunchKernelGGL(trm_mfma_kernel, dim3(blocks), dim3(BLK), 0, stream, p, wf);
}